// Round 12
// baseline (215.874 us; speedup 1.0000x reference)
//
#include <hip/hip_runtime.h>
#include <cstddef>
#include <cstdint>

// Problem constants (match reference)
#define BATCH 2
#define SEQ 8192
#define CH 256
#define NLM 40
#define MROWS (BATCH * SEQ)   // 16384
#define INV_SCALE 0.0625f     // 1/sqrt(256)
#define NCBLK 256             // colsum blocks per batch (SEQ/32)

typedef unsigned short ushort_t;
typedef __attribute__((ext_vector_type(8))) short short8;    // 8 bf16 (4 VGPRs)
typedef __attribute__((ext_vector_type(4))) float floatx4;   // MFMA acc

// round-to-nearest-even fp32 -> bf16
__device__ __forceinline__ ushort_t f2bf(float f) {
    unsigned int u = __float_as_uint(f);
    u += 0x7FFFu + ((u >> 16) & 1u);
    return (ushort_t)(u >> 16);
}
__device__ __forceinline__ float bf2f(ushort_t u) {
    return __uint_as_float(((unsigned)u) << 16);
}

// ---------------------------------------------------------------------------
// colsum_kernel: partial[b][blk][c] = sum of 32 rows of col c.
// (R11's convert_colsum minus the xbf write — xbf is eliminated this round;
// gemm_qkv_score converts query fp32->bf16 during LDS staging instead.)
// grid (SEQ/32, B) = 512 blocks, block 256. LDS-reduce 4 row-groups, one
// plain store per column per block (R8 atomic-hotspot lesson).
// ---------------------------------------------------------------------------
__global__ __launch_bounds__(256) void colsum_kernel(const float* __restrict__ x,
                                                     float* __restrict__ partial) {
    __shared__ float red[4][256];
    const int b = blockIdx.y;
    const int r0 = blockIdx.x * 32;
    const int t = threadIdx.x;
    const int c4 = (t & 63) * 4;     // 0..252
    const int rg = t >> 6;           // 0..3
    const float* base = x + ((size_t)b * SEQ + r0) * 256;
    float4 s = {0.f, 0.f, 0.f, 0.f};
#pragma unroll
    for (int i = 0; i < 8; i++) {
        const int r = rg + i * 4;    // 0..31
        const float4 a = *(const float4*)&base[(size_t)r * 256 + c4];
        s.x += a.x; s.y += a.y; s.z += a.z; s.w += a.w;
    }
    *(float4*)&red[rg][c4] = s;
    __syncthreads();
    const float tot = red[0][t] + red[1][t] + red[2][t] + red[3][t];
    partial[((size_t)b * NCBLK + blockIdx.x) * 256 + t] = tot;
}

// ---------------------------------------------------------------------------
// ws_kernel: ranking vector in fp32. Also zeros tmat (memset folded in).
//   phase 0: xs[c] = sum_blk partial[b][blk][c]
//   phase 1: qs = Wq @ xs + N*bq ;  phase 2: ws[b] = Wk^T @ qs
// grid (B), block 1024.
// ---------------------------------------------------------------------------
__global__ __launch_bounds__(1024) void ws_kernel(const float* __restrict__ partial,
                                                  const float* __restrict__ Wq,
                                                  const float* __restrict__ bq,
                                                  const float* __restrict__ Wk,
                                                  float* __restrict__ ws,
                                                  float* __restrict__ tmat) {
    const int b = blockIdx.x;
    __shared__ float xs[256];
    __shared__ float qs[256];
    __shared__ float ppart[4][256];
    const int t = threadIdx.x;
    {
        float* tz = tmat + (size_t)b * NLM * 256;
        for (int i = t; i < NLM * 256; i += 1024) tz[i] = 0.f;
    }
    {
        const int c = t & 255, qd = t >> 8;
        const float* pb = partial + ((size_t)b * NCBLK + qd * 64) * 256 + c;
        float a = 0.f;
#pragma unroll 8
        for (int i = 0; i < 64; i++) a += pb[(size_t)i * 256];
        ppart[qd][c] = a;
    }
    __syncthreads();
    if (t < 256) xs[t] = ppart[0][t] + ppart[1][t] + ppart[2][t] + ppart[3][t];
    __syncthreads();
    const int lane = t & 63, w = t >> 6;
    for (int g = 0; g < 16; g++) {
        const int o = w * 16 + g;
        const float4 wq = *(const float4*)&Wq[(size_t)o * 256 + lane * 4];
        const float4 x4 = *(const float4*)&xs[lane * 4];
        float d = wq.x * x4.x + wq.y * x4.y + wq.z * x4.z + wq.w * x4.w;
#pragma unroll
        for (int off = 32; off >= 1; off >>= 1) d += __shfl_down(d, off);
        if (lane == 0) qs[o] = d + 8192.0f * bq[o];
    }
    __syncthreads();
    const int c = t & 255, part = t >> 8;
    float a = 0.f;
    for (int o = part * 64; o < part * 64 + 64; o++)
        a += Wk[(size_t)o * 256 + c] * qs[o];
    ppart[part][c] = a;
    __syncthreads();
    if (t < 256)
        ws[b * 256 + t] = ppart[0][t] + ppart[1][t] + ppart[2][t] + ppart[3][t];
}

// ---------------------------------------------------------------------------
// gemm_qkv_score: grid (4, 128, 4).
//   z<3: q/k/v projection — A staged DIRECTLY from fp32 query with f2bf in
//        the staging loop (xbf eliminated; identical RNE values -> q/k/v
//        bit-identical to R11). W also converted during staging. bf16 out
//        via LDS-transpose epilogue.
//   z=3: score slice — score[b][m] = dot(query[m], ws[b])/16, fp32 path
//        (ranking precision), bit-identical to R10/R11.
// ---------------------------------------------------------------------------
__global__ __launch_bounds__(256) void gemm_qkv_score(const float* __restrict__ query,
                                                      const float* __restrict__ Wq,
                                                      const float* __restrict__ Wk,
                                                      const float* __restrict__ Wv,
                                                      const float* __restrict__ bq,
                                                      const float* __restrict__ bk,
                                                      const float* __restrict__ bv,
                                                      ushort_t* __restrict__ qkv,
                                                      const float* __restrict__ ws,
                                                      float* __restrict__ score) {
    __shared__ __align__(16) ushort_t As[128 * 72];  // staging uses 128*40
    __shared__ __align__(16) ushort_t Bs[64 * 40];
    const int z = blockIdx.z;
    const int t = threadIdx.x;
    const int lane = t & 63;
    const int w = t >> 6;

    if (z == 3) {  // score slice
        const int blk = blockIdx.y * 4 + blockIdx.x;      // 0..511
#pragma unroll
        for (int i = 0; i < 8; i++) {
            const int g = blk * 32 + i * 4 + w;           // row 0..16383
            const int b = g >> 13;
            const int m = g & 8191;
            const float4 kv = *(const float4*)&query[(size_t)g * 256 + lane * 4];
            const float4 qs = *(const float4*)&ws[b * 256 + lane * 4];
            float d = kv.x * qs.x + kv.y * qs.y + kv.z * qs.z + kv.w * qs.w;
#pragma unroll
            for (int off = 32; off >= 1; off >>= 1) d += __shfl_down(d, off);
            if (lane == 0) score[(size_t)b * SEQ + m] = d * INV_SCALE;
        }
        return;
    }

    const float* __restrict__ W = (z == 0) ? Wq : (z == 1) ? Wk : Wv;
    const float* __restrict__ bias = (z == 0) ? bq : (z == 1) ? bk : bv;
    ushort_t* __restrict__ out = qkv + (size_t)z * MROWS * 256;
    const int o0 = blockIdx.x * 64;
    const int m0 = blockIdx.y * 128;
    const int quad = lane >> 4;
    const int l16 = lane & 15;

    floatx4 acc[2][4];
#pragma unroll
    for (int rt = 0; rt < 2; rt++)
#pragma unroll
        for (int ct = 0; ct < 4; ct++) acc[rt][ct] = (floatx4){0.f, 0.f, 0.f, 0.f};

    for (int kc = 0; kc < 256; kc += 32) {
        // Stage A tile from fp32 query: 512 groups of 8 floats, 2/thread
#pragma unroll
        for (int u = 0; u < 2; u++) {
            const int cid = t + u * 256;
            const int row = cid >> 2, off = cid & 3;
            const float* xp = &query[(size_t)(m0 + row) * 256 + kc + off * 8];
            const float4 a = *(const float4*)xp;
            const float4 c = *(const float4*)(xp + 4);
            uint4 o;
            o.x = f2bf(a.x) | ((unsigned)f2bf(a.y) << 16);
            o.y = f2bf(a.z) | ((unsigned)f2bf(a.w) << 16);
            o.z = f2bf(c.x) | ((unsigned)f2bf(c.y) << 16);
            o.w = f2bf(c.z) | ((unsigned)f2bf(c.w) << 16);
            *(uint4*)&As[row * 40 + off * 8] = o;
        }
        // Stage W tile fp32 -> bf16
        {
            const int row = t >> 2, off = t & 3;
            const float* wp = &W[(size_t)(o0 + row) * 256 + kc + off * 8];
            const float4 a = *(const float4*)wp;
            const float4 c = *(const float4*)(wp + 4);
            uint4 o;
            o.x = f2bf(a.x) | ((unsigned)f2bf(a.y) << 16);
            o.y = f2bf(a.z) | ((unsigned)f2bf(a.w) << 16);
            o.z = f2bf(c.x) | ((unsigned)f2bf(c.y) << 16);
            o.w = f2bf(c.z) | ((unsigned)f2bf(c.w) << 16);
            *(uint4*)&Bs[row * 40 + off * 8] = o;
        }
        __syncthreads();
        short8 a[2], b[4];
#pragma unroll
        for (int rt = 0; rt < 2; rt++)
            a[rt] = *(const short8*)&As[(w * 32 + rt * 16 + l16) * 40 + quad * 8];
#pragma unroll
        for (int ct = 0; ct < 4; ct++)
            b[ct] = *(const short8*)&Bs[(ct * 16 + l16) * 40 + quad * 8];
#pragma unroll
        for (int rt = 0; rt < 2; rt++)
#pragma unroll
            for (int ct = 0; ct < 4; ct++)
                acc[rt][ct] = __builtin_amdgcn_mfma_f32_16x16x32_bf16(
                    a[rt], b[ct], acc[rt][ct], 0, 0, 0);
        __syncthreads();
    }

    // Epilogue: bias + bf16 into As (stride 72), then coalesced uint4 stores
#pragma unroll
    for (int rt = 0; rt < 2; rt++) {
#pragma unroll
        for (int ct = 0; ct < 4; ct++) {
            const int col = ct * 16 + l16;
            const float bb = bias[o0 + col];
#pragma unroll
            for (int reg = 0; reg < 4; reg++) {
                const int row = w * 32 + rt * 16 + quad * 4 + reg;
                As[row * 72 + col] = f2bf(acc[rt][ct][reg] + bb);
            }
        }
    }
    __syncthreads();
#pragma unroll
    for (int u = 0; u < 4; u++) {
        const int cid = t + u * 256;            // 0..1023
        const int row = cid >> 3;               // 0..127
        const int off = (cid & 7) * 8;          // 0..56 (ushorts)
        *(uint4*)&out[(size_t)(m0 + row) * 256 + o0 + off] =
            *(const uint4*)&As[row * 72 + off];
    }
}

// ---------------------------------------------------------------------------
// Top-40 + gather via RADIX-SELECT (R6-verified). grid (B), block 1024.
// kmat bf16; sel written fp32.
// ---------------------------------------------------------------------------
__global__ __launch_bounds__(1024) void topk_gather(const float* __restrict__ score,
                                                    const ushort_t* __restrict__ kmat,
                                                    float* __restrict__ sel) {
    const int b = blockIdx.x;
    const int t = threadIdx.x;
    __shared__ unsigned hist[256];
    __shared__ unsigned wsum[64];
    __shared__ unsigned sPrefix, sMask, sRem, sNeq;
    __shared__ int sNgt;
    __shared__ int top[NLM];
    __shared__ unsigned topkey[NLM];

    unsigned key[8];
#pragma unroll
    for (int j = 0; j < 8; j++) {
        const unsigned u = __float_as_uint(score[(size_t)b * SEQ + t + j * 1024]);
        key[j] = u ^ (unsigned)(((int)u >> 31) | 0x80000000);
    }
    if (t == 0) { sPrefix = 0; sMask = 0; sRem = NLM; sNgt = 0; sNeq = 0; }

    for (int lvl = 0; lvl < 4; lvl++) {
        const int shift = 24 - 8 * lvl;
        if (t < 256) hist[t] = 0;
        __syncthreads();
        const unsigned pfx = sPrefix, msk = sMask;
#pragma unroll
        for (int j = 0; j < 8; j++)
            if (((key[j] ^ pfx) & msk) == 0)
                atomicAdd(&hist[(key[j] >> shift) & 255u], 1u);
        __syncthreads();
        if (t < 64) wsum[t] = hist[t * 4] + hist[t * 4 + 1] + hist[t * 4 + 2] + hist[t * 4 + 3];
        __syncthreads();
        if (t == 0) {
            unsigned rem = sRem, cum = 0;
            int g = 63;
            for (; g > 0; g--) { if (cum + wsum[g] >= rem) break; cum += wsum[g]; }
            int d = g * 4 + 3;
            for (; d > g * 4; d--) { if (cum + hist[d] >= rem) break; cum += hist[d]; }
            sRem = rem - cum;
            sPrefix |= ((unsigned)d) << shift;
            sMask |= 255u << shift;
        }
        __syncthreads();
    }
    const unsigned K40 = sPrefix;
    const unsigned rem = sRem;
    const int ngt = NLM - (int)rem;

#pragma unroll
    for (int j = 0; j < 8; j++) {
        if (key[j] > K40) {
            const int slot = atomicAdd(&sNgt, 1);
            top[slot] = t + j * 1024; topkey[slot] = key[j];
        } else if (key[j] == K40) {
            const unsigned e = atomicAdd(&sNeq, 1u);
            if (e < rem) {
                const int slot = ngt + (int)e;
                top[slot] = t + j * 1024; topkey[slot] = key[j];
            }
        }
    }
    __syncthreads();

    if (t < 64) {
        unsigned long long c = (t < NLM)
            ? ((((unsigned long long)(~topkey[t])) << 32) | (unsigned)top[t])
            : 0xFFFFFFFFFFFFFFFFull;
#pragma unroll
        for (int kk = 2; kk <= 64; kk <<= 1) {
#pragma unroll
            for (int j = kk >> 1; j >= 1; j >>= 1) {
                const unsigned long long o = __shfl_xor(c, j);
                const bool takeMin = ((t & kk) == 0) == ((t & j) == 0);
                const bool less = c < o;
                c = (takeMin == less) ? c : o;
            }
        }
        if (t < NLM) top[t] = (int)(c & 0xFFFFFFFFu);
    }
    __syncthreads();

    for (int f = t; f < NLM * 256; f += 1024) {
        const int j = f >> 8;
        const int cc = f & 255;
        sel[(size_t)b * NLM * 256 + f] = bf2f(kmat[((size_t)b * SEQ + top[j]) * 256 + cc]);
    }
}

// ---------------------------------------------------------------------------
// sim_fused: grid (SEQ/64, B, 2), block 256. (R11-verified)
//   z=0: logits+softmax vs q -> write simq.
//   z=1: logits+softmax vs k -> tmat accumulation in-place (simk on-chip).
// LDS union: phase A (As_ 17.4K + St_ 10.9K) / phase B (Ps 10K + Vs 32K).
// ---------------------------------------------------------------------------
__global__ __launch_bounds__(256, 4) void sim_fused(const ushort_t* __restrict__ qbf,
                                                    const ushort_t* __restrict__ kbf,
                                                    const ushort_t* __restrict__ vbf,
                                                    const float* __restrict__ sel,
                                                    float* __restrict__ simq,
                                                    float* __restrict__ tmat) {
    __shared__ __align__(16) char smem[43008];
    float (*As_)[68] = (float(*)[68])smem;              // phase A: 17408 B
    float (*St_)[68] = (float(*)[68])(smem + 17408);    // phase A: 10880 B
    float (*Ps)[40]  = (float(*)[40])smem;              // phase B: 10240 B
    ushort_t* Vs     = (ushort_t*)(smem + 10240);       // phase B: 32768 B
    const int b = blockIdx.y;
    const int n0 = blockIdx.x * 64;
    const int t = threadIdx.x;
    const int r = t >> 2, c = t & 3;
    const ushort_t* __restrict__ A = (blockIdx.z == 0) ? qbf : kbf;
    const ushort_t* __restrict__ Arow = A + ((size_t)b * SEQ + n0) * 256;
    const float* __restrict__ Sb = sel + (size_t)b * NLM * 256;

    float acc[10];
#pragma unroll
    for (int j = 0; j < 10; j++) acc[j] = 0.f;

    for (int kc = 0; kc < 256; kc += 64) {
#pragma unroll
        for (int u = 0; u < 4; u++) {
            const int f = t + u * 256;
            const int row = f >> 4;
            const int c4 = (f & 15) * 4;
            const uint2 raw = *(const uint2*)&Arow[(size_t)row * 256 + kc + c4];
            float4 fa;
            fa.x = __uint_as_float((raw.x & 0xFFFFu) << 16);
            fa.y = __uint_as_float(raw.x & 0xFFFF0000u);
            fa.z = __uint_as_float((raw.y & 0xFFFFu) << 16);
            fa.w = __uint_as_float(raw.y & 0xFFFF0000u);
            *(float4*)&As_[row][c4] = fa;
        }
#pragma unroll
        for (int u = 0; u < 3; u++) {
            const int f = t + u * 256;
            if (f < 640) {
                const int row = f >> 4;
                const int c4 = (f & 15) * 4;
                *(float4*)&St_[row][c4] = *(const float4*)&Sb[(size_t)row * 256 + kc + c4];
            }
        }
        __syncthreads();
#pragma unroll 1
        for (int i = 0; i < 64; i += 4) {
            const float4 a = *(const float4*)&As_[r][i];
#pragma unroll
            for (int j = 0; j < 10; j++) {
                const float4 s = *(const float4*)&St_[c * 10 + j][i];
                acc[j] = fmaf(a.x, s.x, acc[j]);
                acc[j] = fmaf(a.y, s.y, acc[j]);
                acc[j] = fmaf(a.z, s.z, acc[j]);
                acc[j] = fmaf(a.w, s.w, acc[j]);
            }
        }
        __syncthreads();
    }

    float mx = -1e30f;
#pragma unroll
    for (int j = 0; j < 10; j++) {
        acc[j] *= INV_SCALE;
        mx = fmaxf(mx, acc[j]);
    }
    mx = fmaxf(mx, __shfl_xor(mx, 1));
    mx = fmaxf(mx, __shfl_xor(mx, 2));
    float sum = 0.f;
#pragma unroll
    for (int j = 0; j < 10; j++) {
        acc[j] = expf(acc[j] - mx);
        sum += acc[j];
    }
    sum += __shfl_xor(sum, 1);
    sum += __shfl_xor(sum, 2);
    const float inv = 1.f / sum;
#pragma unroll
    for (int j = 0; j < 10; j++) acc[j] *= inv;

    if (blockIdx.z == 0) {
        float* __restrict__ dst = &simq[((size_t)b * SEQ + n0 + r) * NLM + c * 10];
#pragma unroll
        for (int j2 = 0; j2 < 5; j2++) {
            float2 o; o.x = acc[2 * j2]; o.y = acc[2 * j2 + 1];
            *(float2*)&dst[2 * j2] = o;
        }
        return;
    }

    // ---- z=1: tmat accumulation in-place (simk stays on-chip) ----
#pragma unroll
    for (int j = 0; j < 10; j++) Ps[r][c * 10 + j] = acc[j];
#pragma unroll
    for (int u = 0; u < 8; u++) {
        const int cid = t + u * 256;          // 0..2047
        const int row = cid >> 5, off = (cid & 31) * 8;
        *(uint4*)&Vs[row * 256 + off] =
            *(const uint4*)&vbf[((size_t)b * SEQ + n0 + row) * 256 + off];
    }
    __syncthreads();

    float tac[40];
#pragma unroll
    for (int j = 0; j < 40; j++) tac[j] = 0.f;

#pragma unroll 2
    for (int m = 0; m < 64; m++) {
        const float vv = bf2f(Vs[m * 256 + t]);   // 2-way bank alias: free
#pragma unroll
        for (int j4 = 0; j4 < 10; j4++) {
            const float4 p = *(const float4*)&Ps[m][j4 * 4];  // broadcast
            tac[j4 * 4 + 0] = fmaf(p.x, vv, tac[j4 * 4 + 0]);
            tac[j4 * 4 + 1] = fmaf(p.y, vv, tac[j4 * 4 + 1]);
            tac[j4 * 4 + 2] = fmaf(p.z, vv, tac[j4 * 4 + 2]);
            tac[j4 * 4 + 3] = fmaf(p.w, vv, tac[j4 * 4 + 3]);
        }
    }
#pragma unroll
    for (int j = 0; j < 40; j++)
        atomicAdd(&tmat[(size_t)b * NLM * 256 + j * 256 + t], tac[j]);
}

// ---------------------------------------------------------------------------
// tw_kernel: TW[b][l][c] = sum_o tmat[b][l][o] * Wo[c][o]   (reassociation:
// out = (simq@tmat)@Wo^T = simq@(tmat@Wo^T) — replaces out_pre + gemm_out's
// MFMA pass, and upgrades the landmark contraction to fp32).
// grid (4, B), block 256: block handles 10 landmarks; thread t owns column c=t
// streaming its own Wo row (L1-resident: 256 lines x 64 B = 16 KB active set).
// tmat slice broadcast from LDS. tw[10] accumulators, bounded unroll.
// ---------------------------------------------------------------------------
__global__ __launch_bounds__(256) void tw_kernel(const float* __restrict__ tmat,
                                                 const float* __restrict__ Wo,
                                                 float* __restrict__ TW) {
    __shared__ float Ps[10][256];
    const int b = blockIdx.y;
    const int lg = blockIdx.x;    // landmark group: lm = lg*10 .. lg*10+9
    const int t = threadIdx.x;
    float* pflat = &Ps[0][0];
    for (int f = t; f < 10 * 256; f += 256)
        pflat[f] = tmat[(size_t)b * NLM * 256 + lg * 10 * 256 + f];
    __syncthreads();

    float tw[10];
#pragma unroll
    for (int j = 0; j < 10; j++) tw[j] = 0.f;
    const float* __restrict__ wrow = &Wo[(size_t)t * 256];
#pragma unroll 4
    for (int o = 0; o < 256; o++) {
        const float wo = wrow[o];
#pragma unroll
        for (int j = 0; j < 10; j++) tw[j] = fmaf(Ps[j][o], wo, tw[j]);  // broadcast
    }
#pragma unroll
    for (int j = 0; j < 10; j++)
        TW[(size_t)b * NLM * 256 + (lg * 10 + j) * 256 + t] = tw[j];
}

// ---------------------------------------------------------------------------
// out_final: out[g][c] = sum_l simq[g][l]*TW[b][l][c] + bo[c] + resid[g][c].
// grid (MROWS/64), block 256 — out_pre's verified structure with the
// bias+residual epilogue folded in; writes fp32 d_out directly.
// ---------------------------------------------------------------------------
__global__ __launch_bounds__(256) void out_final(const float* __restrict__ simq,
                                                 const float* __restrict__ TW,
                                                 const float* __restrict__ bo,
                                                 const float* __restrict__ resid,
                                                 float* __restrict__ out) {
    __shared__ float Pm[64][40];
    const int g0 = blockIdx.x * 64;
    const int b = g0 >> 13;
    const int t = threadIdx.x;
    float* pflat = &Pm[0][0];
    for (int f = t; f < 64 * NLM; f += 256) pflat[f] = simq[(size_t)g0 * NLM + f];
    float tc[40];
#pragma unroll
    for (int l = 0; l < 40; l++) tc[l] = TW[(size_t)b * NLM * 256 + l * 256 + t];
    __syncthreads();
    const float bb = bo[t];
#pragma unroll 2
    for (int m = 0; m < 64; m++) {
        float a = 0.f;
#pragma unroll
        for (int j4 = 0; j4 < 10; j4++) {
            const float4 p = *(const float4*)&Pm[m][j4 * 4];  // broadcast
            a = fmaf(p.x, tc[j4 * 4 + 0], a);
            a = fmaf(p.y, tc[j4 * 4 + 1], a);
            a = fmaf(p.z, tc[j4 * 4 + 2], a);
            a = fmaf(p.w, tc[j4 * 4 + 3], a);
        }
        out[((size_t)g0 + m) * 256 + t] =
            a + bb + resid[((size_t)g0 + m) * 256 + t];
    }
}

// ---------------------------------------------------------------------------
// Workspace (~29 MB). 7 dispatches. vs R11: xbf & outp_bf eliminated
// (conversion folded into gemm staging; output projection reassociated via
// TW so out_pre+gemm_out became tw_kernel+out_final).
// ---------------------------------------------------------------------------
extern "C" void kernel_launch(void* const* d_in, const int* in_sizes, int n_in,
                              void* d_out, int out_size, void* d_ws, size_t ws_size,
                              hipStream_t stream) {
    const float* query = (const float*)d_in[0];
    const float* Wq = (const float*)d_in[1];
    const float* bq = (const float*)d_in[2];
    const float* Wk = (const float*)d_in[3];
    const float* bk = (const float*)d_in[4];
    const float* Wv = (const float*)d_in[5];
    const float* bv = (const float*)d_in[6];
    const float* Wo = (const float*)d_in[7];
    const float* bo = (const float*)d_in[8];
    float* out = (float*)d_out;

    char* p = (char*)d_ws;
    float* simq  = (float*)p;            p += (size_t)MROWS * NLM * 4;      // 2.62 MB
    float* sel   = (float*)p;            p += (size_t)BATCH * NLM * 256 * 4;
    float* tmat  = (float*)p;            p += (size_t)BATCH * NLM * 256 * 4;
    float* TW    = (float*)p;            p += (size_t)BATCH * NLM * 256 * 4;
    float* partial = (float*)p;          p += (size_t)BATCH * NCBLK * 256 * 4; // 512 KB
    float* ws    = (float*)p;            p += (size_t)BATCH * 256 * 4;
    float* score = (float*)p;            p += (size_t)BATCH * SEQ * 4;
    ushort_t* qkv = (ushort_t*)p;        p += (size_t)3 * MROWS * 256 * 2;  // 25.2 MB
    ushort_t* qbf = qkv;
    ushort_t* kbf = qkv + (size_t)MROWS * 256;
    ushort_t* vbf = qkv + (size_t)2 * MROWS * 256;

    const dim3 blk(256);

    colsum_kernel<<<dim3(SEQ / 32, BATCH), blk, 0, stream>>>(query, partial);
    ws_kernel<<<dim3(BATCH), dim3(1024), 0, stream>>>(partial, Wq, bq, Wk, ws, tmat);

    gemm_qkv_score<<<dim3(4, MROWS / 128, 4), blk, 0, stream>>>(
        query, Wq, Wk, Wv, bq, bk, bv, qkv, ws, score);

    topk_gather<<<dim3(BATCH), dim3(1024), 0, stream>>>(score, kbf, sel);

    sim_fused<<<dim3(SEQ / 64, BATCH, 2), blk, 0, stream>>>(qbf, kbf, vbf, sel, simq, tmat);

    tw_kernel<<<dim3(4, BATCH), blk, 0, stream>>>(tmat, Wo, TW);
    out_final<<<dim3(MROWS / 64), blk, 0, stream>>>(simq, TW, bo, query, out);
}

// Round 13
// 211.582 us; speedup vs baseline: 1.0203x; 1.0203x over previous
//
#include <hip/hip_runtime.h>
#include <cstddef>
#include <cstdint>

// Problem constants (match reference)
#define BATCH 2
#define SEQ 8192
#define CH 256
#define NLM 40
#define MROWS (BATCH * SEQ)   // 16384
#define INV_SCALE 0.0625f     // 1/sqrt(256)
#define NCBLK 256             // convert_colsum blocks per batch (SEQ/32)

typedef unsigned short ushort_t;
typedef __attribute__((ext_vector_type(8))) short short8;    // 8 bf16 (4 VGPRs)
typedef __attribute__((ext_vector_type(4))) float floatx4;   // MFMA acc

// round-to-nearest-even fp32 -> bf16
__device__ __forceinline__ ushort_t f2bf(float f) {
    unsigned int u = __float_as_uint(f);
    u += 0x7FFFu + ((u >> 16) & 1u);
    return (ushort_t)(u >> 16);
}
__device__ __forceinline__ float bf2f(ushort_t u) {
    return __uint_as_float(((unsigned)u) << 16);
}

// ---------------------------------------------------------------------------
// convert_colsum: xbf = bf16(x); partial[b][blk][c] = sum of 32 rows of col c.
// grid (SEQ/32, B) = 512 blocks, block 256. LDS-reduce 4 row-groups, one
// plain store per column per block (R8 atomic-hotspot lesson).
// R12 POST-MORTEM: eliminating xbf and converting inside the 3 GEMM z-slices
// cost ~20 us (2x A-staging bytes + 3x conversion work). A conversion shared
// by 3 consumers belongs in its own streaming pass — reinstated here.
// ---------------------------------------------------------------------------
__global__ __launch_bounds__(256) void convert_colsum(const float* __restrict__ x,
                                                      ushort_t* __restrict__ xbf,
                                                      float* __restrict__ partial) {
    __shared__ float red[4][256];
    const int b = blockIdx.y;
    const int r0 = blockIdx.x * 32;
    const int t = threadIdx.x;
    const int c4 = (t & 63) * 4;     // 0..252
    const int rg = t >> 6;           // 0..3
    const float* base = x + ((size_t)b * SEQ + r0) * 256;
    ushort_t* obase = xbf + ((size_t)b * SEQ + r0) * 256;
    float4 s = {0.f, 0.f, 0.f, 0.f};
#pragma unroll
    for (int i = 0; i < 8; i++) {
        const int r = rg + i * 4;    // 0..31
        const float4 a = *(const float4*)&base[(size_t)r * 256 + c4];
        uint2 o;
        o.x = f2bf(a.x) | ((unsigned)f2bf(a.y) << 16);
        o.y = f2bf(a.z) | ((unsigned)f2bf(a.w) << 16);
        *(uint2*)&obase[(size_t)r * 256 + c4] = o;
        s.x += a.x; s.y += a.y; s.z += a.z; s.w += a.w;
    }
    *(float4*)&red[rg][c4] = s;
    __syncthreads();
    const float tot = red[0][t] + red[1][t] + red[2][t] + red[3][t];
    partial[((size_t)b * NCBLK + blockIdx.x) * 256 + t] = tot;
}

// ---------------------------------------------------------------------------
// ws_kernel: ranking vector in fp32. Also zeros tmat (memset folded in).
//   phase 0: xs[c] = sum_blk partial[b][blk][c]
//   phase 1: qs = Wq @ xs + N*bq ;  phase 2: ws[b] = Wk^T @ qs
// grid (B), block 1024.
// ---------------------------------------------------------------------------
__global__ __launch_bounds__(1024) void ws_kernel(const float* __restrict__ partial,
                                                  const float* __restrict__ Wq,
                                                  const float* __restrict__ bq,
                                                  const float* __restrict__ Wk,
                                                  float* __restrict__ ws,
                                                  float* __restrict__ tmat) {
    const int b = blockIdx.x;
    __shared__ float xs[256];
    __shared__ float qs[256];
    __shared__ float ppart[4][256];
    const int t = threadIdx.x;
    {
        float* tz = tmat + (size_t)b * NLM * 256;
        for (int i = t; i < NLM * 256; i += 1024) tz[i] = 0.f;
    }
    {
        const int c = t & 255, qd = t >> 8;
        const float* pb = partial + ((size_t)b * NCBLK + qd * 64) * 256 + c;
        float a = 0.f;
#pragma unroll 8
        for (int i = 0; i < 64; i++) a += pb[(size_t)i * 256];
        ppart[qd][c] = a;
    }
    __syncthreads();
    if (t < 256) xs[t] = ppart[0][t] + ppart[1][t] + ppart[2][t] + ppart[3][t];
    __syncthreads();
    const int lane = t & 63, w = t >> 6;
    for (int g = 0; g < 16; g++) {
        const int o = w * 16 + g;
        const float4 wq = *(const float4*)&Wq[(size_t)o * 256 + lane * 4];
        const float4 x4 = *(const float4*)&xs[lane * 4];
        float d = wq.x * x4.x + wq.y * x4.y + wq.z * x4.z + wq.w * x4.w;
#pragma unroll
        for (int off = 32; off >= 1; off >>= 1) d += __shfl_down(d, off);
        if (lane == 0) qs[o] = d + 8192.0f * bq[o];
    }
    __syncthreads();
    const int c = t & 255, part = t >> 8;
    float a = 0.f;
    for (int o = part * 64; o < part * 64 + 64; o++)
        a += Wk[(size_t)o * 256 + c] * qs[o];
    ppart[part][c] = a;
    __syncthreads();
    if (t < 256)
        ws[b * 256 + t] = ppart[0][t] + ppart[1][t] + ppart[2][t] + ppart[3][t];
}

// ---------------------------------------------------------------------------
// gemm_qkv_score: grid (4, 128, 4).
//   z<3: q/k/v projection — bf16 A from xbf (R11-verified staging), fp32 W
//        converted during staging, bf16 out via LDS-transpose epilogue.
//   z=3: score slice — score[b][m] = dot(query[m], ws[b])/16, fp32 path
//        (ranking precision), bit-identical to R10/R11.
// ---------------------------------------------------------------------------
__global__ __launch_bounds__(256) void gemm_qkv_score(const ushort_t* __restrict__ xbf,
                                                      const float* __restrict__ Wq,
                                                      const float* __restrict__ Wk,
                                                      const float* __restrict__ Wv,
                                                      const float* __restrict__ bq,
                                                      const float* __restrict__ bk,
                                                      const float* __restrict__ bv,
                                                      ushort_t* __restrict__ qkv,
                                                      const float* __restrict__ query,
                                                      const float* __restrict__ ws,
                                                      float* __restrict__ score) {
    __shared__ __align__(16) ushort_t As[128 * 72];  // staging uses 128*40
    __shared__ __align__(16) ushort_t Bs[64 * 40];
    const int z = blockIdx.z;
    const int t = threadIdx.x;
    const int lane = t & 63;
    const int w = t >> 6;

    if (z == 3) {  // score slice
        const int blk = blockIdx.y * 4 + blockIdx.x;      // 0..511
#pragma unroll
        for (int i = 0; i < 8; i++) {
            const int g = blk * 32 + i * 4 + w;           // row 0..16383
            const int b = g >> 13;
            const int m = g & 8191;
            const float4 kv = *(const float4*)&query[(size_t)g * 256 + lane * 4];
            const float4 qs = *(const float4*)&ws[b * 256 + lane * 4];
            float d = kv.x * qs.x + kv.y * qs.y + kv.z * qs.z + kv.w * qs.w;
#pragma unroll
            for (int off = 32; off >= 1; off >>= 1) d += __shfl_down(d, off);
            if (lane == 0) score[(size_t)b * SEQ + m] = d * INV_SCALE;
        }
        return;
    }

    const float* __restrict__ W = (z == 0) ? Wq : (z == 1) ? Wk : Wv;
    const float* __restrict__ bias = (z == 0) ? bq : (z == 1) ? bk : bv;
    ushort_t* __restrict__ out = qkv + (size_t)z * MROWS * 256;
    const int o0 = blockIdx.x * 64;
    const int m0 = blockIdx.y * 128;
    const int quad = lane >> 4;
    const int l16 = lane & 15;

    floatx4 acc[2][4];
#pragma unroll
    for (int rt = 0; rt < 2; rt++)
#pragma unroll
        for (int ct = 0; ct < 4; ct++) acc[rt][ct] = (floatx4){0.f, 0.f, 0.f, 0.f};

    for (int kc = 0; kc < 256; kc += 32) {
        // Stage A tile: 128 rows x 32 k bf16 (16 B/thread — the R12 fp32
        // staging at 32 B/thread + in-loop convert was the regression)
#pragma unroll
        for (int u = 0; u < 2; u++) {
            const int cid = t + u * 256;
            const int row = cid >> 2, off = cid & 3;
            *(uint4*)&As[row * 40 + off * 8] =
                *(const uint4*)&xbf[(size_t)(m0 + row) * 256 + kc + off * 8];
        }
        // Stage W tile fp32 -> bf16
        {
            const int row = t >> 2, off = t & 3;
            const float* wp = &W[(size_t)(o0 + row) * 256 + kc + off * 8];
            const float4 a = *(const float4*)wp;
            const float4 c = *(const float4*)(wp + 4);
            uint4 o;
            o.x = f2bf(a.x) | ((unsigned)f2bf(a.y) << 16);
            o.y = f2bf(a.z) | ((unsigned)f2bf(a.w) << 16);
            o.z = f2bf(c.x) | ((unsigned)f2bf(c.y) << 16);
            o.w = f2bf(c.z) | ((unsigned)f2bf(c.w) << 16);
            *(uint4*)&Bs[row * 40 + off * 8] = o;
        }
        __syncthreads();
        short8 a[2], b[4];
#pragma unroll
        for (int rt = 0; rt < 2; rt++)
            a[rt] = *(const short8*)&As[(w * 32 + rt * 16 + l16) * 40 + quad * 8];
#pragma unroll
        for (int ct = 0; ct < 4; ct++)
            b[ct] = *(const short8*)&Bs[(ct * 16 + l16) * 40 + quad * 8];
#pragma unroll
        for (int rt = 0; rt < 2; rt++)
#pragma unroll
            for (int ct = 0; ct < 4; ct++)
                acc[rt][ct] = __builtin_amdgcn_mfma_f32_16x16x32_bf16(
                    a[rt], b[ct], acc[rt][ct], 0, 0, 0);
        __syncthreads();
    }

    // Epilogue: bias + bf16 into As (stride 72), then coalesced uint4 stores
#pragma unroll
    for (int rt = 0; rt < 2; rt++) {
#pragma unroll
        for (int ct = 0; ct < 4; ct++) {
            const int col = ct * 16 + l16;
            const float bb = bias[o0 + col];
#pragma unroll
            for (int reg = 0; reg < 4; reg++) {
                const int row = w * 32 + rt * 16 + quad * 4 + reg;
                As[row * 72 + col] = f2bf(acc[rt][ct][reg] + bb);
            }
        }
    }
    __syncthreads();
#pragma unroll
    for (int u = 0; u < 4; u++) {
        const int cid = t + u * 256;            // 0..1023
        const int row = cid >> 3;               // 0..127
        const int off = (cid & 7) * 8;          // 0..56 (ushorts)
        *(uint4*)&out[(size_t)(m0 + row) * 256 + o0 + off] =
            *(const uint4*)&As[row * 72 + off];
    }
}

// ---------------------------------------------------------------------------
// Top-40 + gather via RADIX-SELECT (R6-verified). grid (B), block 1024.
// kmat bf16; sel written fp32.
// ---------------------------------------------------------------------------
__global__ __launch_bounds__(1024) void topk_gather(const float* __restrict__ score,
                                                    const ushort_t* __restrict__ kmat,
                                                    float* __restrict__ sel) {
    const int b = blockIdx.x;
    const int t = threadIdx.x;
    __shared__ unsigned hist[256];
    __shared__ unsigned wsum[64];
    __shared__ unsigned sPrefix, sMask, sRem, sNeq;
    __shared__ int sNgt;
    __shared__ int top[NLM];
    __shared__ unsigned topkey[NLM];

    unsigned key[8];
#pragma unroll
    for (int j = 0; j < 8; j++) {
        const unsigned u = __float_as_uint(score[(size_t)b * SEQ + t + j * 1024]);
        key[j] = u ^ (unsigned)(((int)u >> 31) | 0x80000000);
    }
    if (t == 0) { sPrefix = 0; sMask = 0; sRem = NLM; sNgt = 0; sNeq = 0; }

    for (int lvl = 0; lvl < 4; lvl++) {
        const int shift = 24 - 8 * lvl;
        if (t < 256) hist[t] = 0;
        __syncthreads();
        const unsigned pfx = sPrefix, msk = sMask;
#pragma unroll
        for (int j = 0; j < 8; j++)
            if (((key[j] ^ pfx) & msk) == 0)
                atomicAdd(&hist[(key[j] >> shift) & 255u], 1u);
        __syncthreads();
        if (t < 64) wsum[t] = hist[t * 4] + hist[t * 4 + 1] + hist[t * 4 + 2] + hist[t * 4 + 3];
        __syncthreads();
        if (t == 0) {
            unsigned rem = sRem, cum = 0;
            int g = 63;
            for (; g > 0; g--) { if (cum + wsum[g] >= rem) break; cum += wsum[g]; }
            int d = g * 4 + 3;
            for (; d > g * 4; d--) { if (cum + hist[d] >= rem) break; cum += hist[d]; }
            sRem = rem - cum;
            sPrefix |= ((unsigned)d) << shift;
            sMask |= 255u << shift;
        }
        __syncthreads();
    }
    const unsigned K40 = sPrefix;
    const unsigned rem = sRem;
    const int ngt = NLM - (int)rem;

#pragma unroll
    for (int j = 0; j < 8; j++) {
        if (key[j] > K40) {
            const int slot = atomicAdd(&sNgt, 1);
            top[slot] = t + j * 1024; topkey[slot] = key[j];
        } else if (key[j] == K40) {
            const unsigned e = atomicAdd(&sNeq, 1u);
            if (e < rem) {
                const int slot = ngt + (int)e;
                top[slot] = t + j * 1024; topkey[slot] = key[j];
            }
        }
    }
    __syncthreads();

    if (t < 64) {
        unsigned long long c = (t < NLM)
            ? ((((unsigned long long)(~topkey[t])) << 32) | (unsigned)top[t])
            : 0xFFFFFFFFFFFFFFFFull;
#pragma unroll
        for (int kk = 2; kk <= 64; kk <<= 1) {
#pragma unroll
            for (int j = kk >> 1; j >= 1; j >>= 1) {
                const unsigned long long o = __shfl_xor(c, j);
                const bool takeMin = ((t & kk) == 0) == ((t & j) == 0);
                const bool less = c < o;
                c = (takeMin == less) ? c : o;
            }
        }
        if (t < NLM) top[t] = (int)(c & 0xFFFFFFFFu);
    }
    __syncthreads();

    for (int f = t; f < NLM * 256; f += 1024) {
        const int j = f >> 8;
        const int cc = f & 255;
        sel[(size_t)b * NLM * 256 + f] = bf2f(kmat[((size_t)b * SEQ + top[j]) * 256 + cc]);
    }
}

// ---------------------------------------------------------------------------
// sim_fused: grid (SEQ/64, B, 2), block 256. (R11-verified)
//   z=0: logits+softmax vs q -> write simq.
//   z=1: logits+softmax vs k -> tmat accumulation in-place (simk on-chip).
// LDS union: phase A (As_ 17.4K + St_ 10.9K) / phase B (Ps 10K + Vs 32K).
// ---------------------------------------------------------------------------
__global__ __launch_bounds__(256, 4) void sim_fused(const ushort_t* __restrict__ qbf,
                                                    const ushort_t* __restrict__ kbf,
                                                    const ushort_t* __restrict__ vbf,
                                                    const float* __restrict__ sel,
                                                    float* __restrict__ simq,
                                                    float* __restrict__ tmat) {
    __shared__ __align__(16) char smem[43008];
    float (*As_)[68] = (float(*)[68])smem;              // phase A: 17408 B
    float (*St_)[68] = (float(*)[68])(smem + 17408);    // phase A: 10880 B
    float (*Ps)[40]  = (float(*)[40])smem;              // phase B: 10240 B
    ushort_t* Vs     = (ushort_t*)(smem + 10240);       // phase B: 32768 B
    const int b = blockIdx.y;
    const int n0 = blockIdx.x * 64;
    const int t = threadIdx.x;
    const int r = t >> 2, c = t & 3;
    const ushort_t* __restrict__ A = (blockIdx.z == 0) ? qbf : kbf;
    const ushort_t* __restrict__ Arow = A + ((size_t)b * SEQ + n0) * 256;
    const float* __restrict__ Sb = sel + (size_t)b * NLM * 256;

    float acc[10];
#pragma unroll
    for (int j = 0; j < 10; j++) acc[j] = 0.f;

    for (int kc = 0; kc < 256; kc += 64) {
#pragma unroll
        for (int u = 0; u < 4; u++) {
            const int f = t + u * 256;
            const int row = f >> 4;
            const int c4 = (f & 15) * 4;
            const uint2 raw = *(const uint2*)&Arow[(size_t)row * 256 + kc + c4];
            float4 fa;
            fa.x = __uint_as_float((raw.x & 0xFFFFu) << 16);
            fa.y = __uint_as_float(raw.x & 0xFFFF0000u);
            fa.z = __uint_as_float((raw.y & 0xFFFFu) << 16);
            fa.w = __uint_as_float(raw.y & 0xFFFF0000u);
            *(float4*)&As_[row][c4] = fa;
        }
#pragma unroll
        for (int u = 0; u < 3; u++) {
            const int f = t + u * 256;
            if (f < 640) {
                const int row = f >> 4;
                const int c4 = (f & 15) * 4;
                *(float4*)&St_[row][c4] = *(const float4*)&Sb[(size_t)row * 256 + kc + c4];
            }
        }
        __syncthreads();
#pragma unroll 1
        for (int i = 0; i < 64; i += 4) {
            const float4 a = *(const float4*)&As_[r][i];
#pragma unroll
            for (int j = 0; j < 10; j++) {
                const float4 s = *(const float4*)&St_[c * 10 + j][i];
                acc[j] = fmaf(a.x, s.x, acc[j]);
                acc[j] = fmaf(a.y, s.y, acc[j]);
                acc[j] = fmaf(a.z, s.z, acc[j]);
                acc[j] = fmaf(a.w, s.w, acc[j]);
            }
        }
        __syncthreads();
    }

    float mx = -1e30f;
#pragma unroll
    for (int j = 0; j < 10; j++) {
        acc[j] *= INV_SCALE;
        mx = fmaxf(mx, acc[j]);
    }
    mx = fmaxf(mx, __shfl_xor(mx, 1));
    mx = fmaxf(mx, __shfl_xor(mx, 2));
    float sum = 0.f;
#pragma unroll
    for (int j = 0; j < 10; j++) {
        acc[j] = expf(acc[j] - mx);
        sum += acc[j];
    }
    sum += __shfl_xor(sum, 1);
    sum += __shfl_xor(sum, 2);
    const float inv = 1.f / sum;
#pragma unroll
    for (int j = 0; j < 10; j++) acc[j] *= inv;

    if (blockIdx.z == 0) {
        float* __restrict__ dst = &simq[((size_t)b * SEQ + n0 + r) * NLM + c * 10];
#pragma unroll
        for (int j2 = 0; j2 < 5; j2++) {
            float2 o; o.x = acc[2 * j2]; o.y = acc[2 * j2 + 1];
            *(float2*)&dst[2 * j2] = o;
        }
        return;
    }

    // ---- z=1: tmat accumulation in-place (simk stays on-chip) ----
#pragma unroll
    for (int j = 0; j < 10; j++) Ps[r][c * 10 + j] = acc[j];
#pragma unroll
    for (int u = 0; u < 8; u++) {
        const int cid = t + u * 256;          // 0..2047
        const int row = cid >> 5, off = (cid & 31) * 8;
        *(uint4*)&Vs[row * 256 + off] =
            *(const uint4*)&vbf[((size_t)b * SEQ + n0 + row) * 256 + off];
    }
    __syncthreads();

    float tac[40];
#pragma unroll
    for (int j = 0; j < 40; j++) tac[j] = 0.f;

#pragma unroll 2
    for (int m = 0; m < 64; m++) {
        const float vv = bf2f(Vs[m * 256 + t]);   // 2-way bank alias: free
#pragma unroll
        for (int j4 = 0; j4 < 10; j4++) {
            const float4 p = *(const float4*)&Ps[m][j4 * 4];  // broadcast
            tac[j4 * 4 + 0] = fmaf(p.x, vv, tac[j4 * 4 + 0]);
            tac[j4 * 4 + 1] = fmaf(p.y, vv, tac[j4 * 4 + 1]);
            tac[j4 * 4 + 2] = fmaf(p.z, vv, tac[j4 * 4 + 2]);
            tac[j4 * 4 + 3] = fmaf(p.w, vv, tac[j4 * 4 + 3]);
        }
    }
#pragma unroll
    for (int j = 0; j < 40; j++)
        atomicAdd(&tmat[(size_t)b * NLM * 256 + j * 256 + t], tac[j]);
}

// ---------------------------------------------------------------------------
// tw_kernel: TW[b][l][c] = sum_o tmat[b][l][o] * Wo[c][o]   (reassociation:
// out = (simq@tmat)@Wo^T = simq@(tmat@Wo^T) — kept from R12: replaces the
// out_pre+gemm_out MFMA pass and upgrades the landmark contraction to fp32).
// grid (4, B), block 256.
// ---------------------------------------------------------------------------
__global__ __launch_bounds__(256) void tw_kernel(const float* __restrict__ tmat,
                                                 const float* __restrict__ Wo,
                                                 float* __restrict__ TW) {
    __shared__ float Ps[10][256];
    const int b = blockIdx.y;
    const int lg = blockIdx.x;    // landmark group: lm = lg*10 .. lg*10+9
    const int t = threadIdx.x;
    float* pflat = &Ps[0][0];
    for (int f = t; f < 10 * 256; f += 256)
        pflat[f] = tmat[(size_t)b * NLM * 256 + lg * 10 * 256 + f];
    __syncthreads();

    float tw[10];
#pragma unroll
    for (int j = 0; j < 10; j++) tw[j] = 0.f;
    const float* __restrict__ wrow = &Wo[(size_t)t * 256];
#pragma unroll 4
    for (int o = 0; o < 256; o++) {
        const float wo = wrow[o];
#pragma unroll
        for (int j = 0; j < 10; j++) tw[j] = fmaf(Ps[j][o], wo, tw[j]);  // broadcast
    }
#pragma unroll
    for (int j = 0; j < 10; j++)
        TW[(size_t)b * NLM * 256 + (lg * 10 + j) * 256 + t] = tw[j];
}

// ---------------------------------------------------------------------------
// out_final: out[g][c] = sum_l simq[g][l]*TW[b][l][c] + bo[c] + resid[g][c].
// grid (MROWS/64), block 256.
// ---------------------------------------------------------------------------
__global__ __launch_bounds__(256) void out_final(const float* __restrict__ simq,
                                                 const float* __restrict__ TW,
                                                 const float* __restrict__ bo,
                                                 const float* __restrict__ resid,
                                                 float* __restrict__ out) {
    __shared__ float Pm[64][40];
    const int g0 = blockIdx.x * 64;
    const int b = g0 >> 13;
    const int t = threadIdx.x;
    float* pflat = &Pm[0][0];
    for (int f = t; f < 64 * NLM; f += 256) pflat[f] = simq[(size_t)g0 * NLM + f];
    float tc[40];
#pragma unroll
    for (int l = 0; l < 40; l++) tc[l] = TW[(size_t)b * NLM * 256 + l * 256 + t];
    __syncthreads();
    const float bb = bo[t];
#pragma unroll 2
    for (int m = 0; m < 64; m++) {
        float a = 0.f;
#pragma unroll
        for (int j4 = 0; j4 < 10; j4++) {
            const float4 p = *(const float4*)&Pm[m][j4 * 4];  // broadcast
            a = fmaf(p.x, tc[j4 * 4 + 0], a);
            a = fmaf(p.y, tc[j4 * 4 + 1], a);
            a = fmaf(p.z, tc[j4 * 4 + 2], a);
            a = fmaf(p.w, tc[j4 * 4 + 3], a);
        }
        out[((size_t)g0 + m) * 256 + t] =
            a + bb + resid[((size_t)g0 + m) * 256 + t];
    }
}

// ---------------------------------------------------------------------------
// Workspace (~37 MB). 7 dispatches. R13 = R11 front half (xbf conversion in
// its own pass) + R12 tail (TW reassociation).
// ---------------------------------------------------------------------------
extern "C" void kernel_launch(void* const* d_in, const int* in_sizes, int n_in,
                              void* d_out, int out_size, void* d_ws, size_t ws_size,
                              hipStream_t stream) {
    const float* query = (const float*)d_in[0];
    const float* Wq = (const float*)d_in[1];
    const float* bq = (const float*)d_in[2];
    const float* Wk = (const float*)d_in[3];
    const float* bk = (const float*)d_in[4];
    const float* Wv = (const float*)d_in[5];
    const float* bv = (const float*)d_in[6];
    const float* Wo = (const float*)d_in[7];
    const float* bo = (const float*)d_in[8];
    float* out = (float*)d_out;

    char* p = (char*)d_ws;
    float* simq  = (float*)p;            p += (size_t)MROWS * NLM * 4;      // 2.62 MB
    float* sel   = (float*)p;            p += (size_t)BATCH * NLM * 256 * 4;
    float* tmat  = (float*)p;            p += (size_t)BATCH * NLM * 256 * 4;
    float* TW    = (float*)p;            p += (size_t)BATCH * NLM * 256 * 4;
    float* partial = (float*)p;          p += (size_t)BATCH * NCBLK * 256 * 4; // 512 KB
    float* ws    = (float*)p;            p += (size_t)BATCH * 256 * 4;
    float* score = (float*)p;            p += (size_t)BATCH * SEQ * 4;
    ushort_t* qkv = (ushort_t*)p;        p += (size_t)3 * MROWS * 256 * 2;  // 25.2 MB
    ushort_t* xbf = (ushort_t*)p;        p += (size_t)MROWS * 256 * 2;      // 8.39 MB
    ushort_t* qbf = qkv;
    ushort_t* kbf = qkv + (size_t)MROWS * 256;
    ushort_t* vbf = qkv + (size_t)2 * MROWS * 256;

    const dim3 blk(256);

    convert_colsum<<<dim3(SEQ / 32, BATCH), blk, 0, stream>>>(query, xbf, partial);
    ws_kernel<<<dim3(BATCH), dim3(1024), 0, stream>>>(partial, Wq, bq, Wk, ws, tmat);

    gemm_qkv_score<<<dim3(4, MROWS / 128, 4), blk, 0, stream>>>(
        xbf, Wq, Wk, Wv, bq, bk, bv, qkv, query, ws, score);

    topk_gather<<<dim3(BATCH), dim3(1024), 0, stream>>>(score, kbf, sel);

    sim_fused<<<dim3(SEQ / 64, BATCH, 2), blk, 0, stream>>>(qbf, kbf, vbf, sel, simq, tmat);

    tw_kernel<<<dim3(4, BATCH), blk, 0, stream>>>(tmat, Wo, TW);
    out_final<<<dim3(MROWS / 64), blk, 0, stream>>>(simq, TW, bo, query, out);
}

// Round 14
// 204.524 us; speedup vs baseline: 1.0555x; 1.0345x over previous
//
#include <hip/hip_runtime.h>
#include <cstddef>
#include <cstdint>

// Problem constants (match reference)
#define BATCH 2
#define SEQ 8192
#define CH 256
#define NLM 40
#define MROWS (BATCH * SEQ)   // 16384
#define INV_SCALE 0.0625f     // 1/sqrt(256)
#define NCBLK 256             // convert_colsum blocks per batch (SEQ/32)

typedef unsigned short ushort_t;
typedef __attribute__((ext_vector_type(8))) short short8;    // 8 bf16 (4 VGPRs)
typedef __attribute__((ext_vector_type(4))) float floatx4;   // MFMA acc

// round-to-nearest-even fp32 -> bf16
__device__ __forceinline__ ushort_t f2bf(float f) {
    unsigned int u = __float_as_uint(f);
    u += 0x7FFFu + ((u >> 16) & 1u);
    return (ushort_t)(u >> 16);
}
__device__ __forceinline__ float bf2f(ushort_t u) {
    return __uint_as_float(((unsigned)u) << 16);
}

// ---------------------------------------------------------------------------
// convert_colsum: xbf = bf16(x); partial[b][blk][c] = sum of 32 rows of col c.
// grid (SEQ/32, B) = 512 blocks, block 256. LDS-reduce 4 row-groups, one
// plain store per column per block (R8 atomic-hotspot lesson).
// R12 lesson: xbf conversion shared by 3 GEMM consumers belongs HERE, in its
// own streaming pass — folding it into the GEMMs cost ~20 us.
// ---------------------------------------------------------------------------
__global__ __launch_bounds__(256) void convert_colsum(const float* __restrict__ x,
                                                      ushort_t* __restrict__ xbf,
                                                      float* __restrict__ partial) {
    __shared__ float red[4][256];
    const int b = blockIdx.y;
    const int r0 = blockIdx.x * 32;
    const int t = threadIdx.x;
    const int c4 = (t & 63) * 4;     // 0..252
    const int rg = t >> 6;           // 0..3
    const float* base = x + ((size_t)b * SEQ + r0) * 256;
    ushort_t* obase = xbf + ((size_t)b * SEQ + r0) * 256;
    float4 s = {0.f, 0.f, 0.f, 0.f};
#pragma unroll
    for (int i = 0; i < 8; i++) {
        const int r = rg + i * 4;    // 0..31
        const float4 a = *(const float4*)&base[(size_t)r * 256 + c4];
        uint2 o;
        o.x = f2bf(a.x) | ((unsigned)f2bf(a.y) << 16);
        o.y = f2bf(a.z) | ((unsigned)f2bf(a.w) << 16);
        *(uint2*)&obase[(size_t)r * 256 + c4] = o;
        s.x += a.x; s.y += a.y; s.z += a.z; s.w += a.w;
    }
    *(float4*)&red[rg][c4] = s;
    __syncthreads();
    const float tot = red[0][t] + red[1][t] + red[2][t] + red[3][t];
    partial[((size_t)b * NCBLK + blockIdx.x) * 256 + t] = tot;
}

// ---------------------------------------------------------------------------
// ws_kernel: ranking vector in fp32. Also zeros tmat (memset folded in).
//   phase 0: xs[c] = sum_blk partial[b][blk][c]
//   phase 1: qs = Wq @ xs + N*bq ;  phase 2: ws[b] = Wk^T @ qs
// grid (B), block 1024.
// ---------------------------------------------------------------------------
__global__ __launch_bounds__(1024) void ws_kernel(const float* __restrict__ partial,
                                                  const float* __restrict__ Wq,
                                                  const float* __restrict__ bq,
                                                  const float* __restrict__ Wk,
                                                  float* __restrict__ ws,
                                                  float* __restrict__ tmat) {
    const int b = blockIdx.x;
    __shared__ float xs[256];
    __shared__ float qs[256];
    __shared__ float ppart[4][256];
    const int t = threadIdx.x;
    {
        float* tz = tmat + (size_t)b * NLM * 256;
        for (int i = t; i < NLM * 256; i += 1024) tz[i] = 0.f;
    }
    {
        const int c = t & 255, qd = t >> 8;
        const float* pb = partial + ((size_t)b * NCBLK + qd * 64) * 256 + c;
        float a = 0.f;
#pragma unroll 8
        for (int i = 0; i < 64; i++) a += pb[(size_t)i * 256];
        ppart[qd][c] = a;
    }
    __syncthreads();
    if (t < 256) xs[t] = ppart[0][t] + ppart[1][t] + ppart[2][t] + ppart[3][t];
    __syncthreads();
    const int lane = t & 63, w = t >> 6;
    for (int g = 0; g < 16; g++) {
        const int o = w * 16 + g;
        const float4 wq = *(const float4*)&Wq[(size_t)o * 256 + lane * 4];
        const float4 x4 = *(const float4*)&xs[lane * 4];
        float d = wq.x * x4.x + wq.y * x4.y + wq.z * x4.z + wq.w * x4.w;
#pragma unroll
        for (int off = 32; off >= 1; off >>= 1) d += __shfl_down(d, off);
        if (lane == 0) qs[o] = d + 8192.0f * bq[o];
    }
    __syncthreads();
    const int c = t & 255, part = t >> 8;
    float a = 0.f;
    for (int o = part * 64; o < part * 64 + 64; o++)
        a += Wk[(size_t)o * 256 + c] * qs[o];
    ppart[part][c] = a;
    __syncthreads();
    if (t < 256)
        ws[b * 256 + t] = ppart[0][t] + ppart[1][t] + ppart[2][t] + ppart[3][t];
}

// ---------------------------------------------------------------------------
// gemm_qkv_score: grid (4, 128, 4).
//   z<3: q/k/v projection — bf16 A from xbf, fp32 W converted during staging,
//        bf16 out via LDS-transpose epilogue.
//   z=3: score slice — score[b][m] = dot(query[m], ws[b])/16, fp32 path
//        (ranking precision).
// ---------------------------------------------------------------------------
__global__ __launch_bounds__(256) void gemm_qkv_score(const ushort_t* __restrict__ xbf,
                                                      const float* __restrict__ Wq,
                                                      const float* __restrict__ Wk,
                                                      const float* __restrict__ Wv,
                                                      const float* __restrict__ bq,
                                                      const float* __restrict__ bk,
                                                      const float* __restrict__ bv,
                                                      ushort_t* __restrict__ qkv,
                                                      const float* __restrict__ query,
                                                      const float* __restrict__ ws,
                                                      float* __restrict__ score) {
    __shared__ __align__(16) ushort_t As[128 * 72];  // staging uses 128*40
    __shared__ __align__(16) ushort_t Bs[64 * 40];
    const int z = blockIdx.z;
    const int t = threadIdx.x;
    const int lane = t & 63;
    const int w = t >> 6;

    if (z == 3) {  // score slice
        const int blk = blockIdx.y * 4 + blockIdx.x;      // 0..511
#pragma unroll
        for (int i = 0; i < 8; i++) {
            const int g = blk * 32 + i * 4 + w;           // row 0..16383
            const int b = g >> 13;
            const int m = g & 8191;
            const float4 kv = *(const float4*)&query[(size_t)g * 256 + lane * 4];
            const float4 qs = *(const float4*)&ws[b * 256 + lane * 4];
            float d = kv.x * qs.x + kv.y * qs.y + kv.z * qs.z + kv.w * qs.w;
#pragma unroll
            for (int off = 32; off >= 1; off >>= 1) d += __shfl_down(d, off);
            if (lane == 0) score[(size_t)b * SEQ + m] = d * INV_SCALE;
        }
        return;
    }

    const float* __restrict__ W = (z == 0) ? Wq : (z == 1) ? Wk : Wv;
    const float* __restrict__ bias = (z == 0) ? bq : (z == 1) ? bk : bv;
    ushort_t* __restrict__ out = qkv + (size_t)z * MROWS * 256;
    const int o0 = blockIdx.x * 64;
    const int m0 = blockIdx.y * 128;
    const int quad = lane >> 4;
    const int l16 = lane & 15;

    floatx4 acc[2][4];
#pragma unroll
    for (int rt = 0; rt < 2; rt++)
#pragma unroll
        for (int ct = 0; ct < 4; ct++) acc[rt][ct] = (floatx4){0.f, 0.f, 0.f, 0.f};

    for (int kc = 0; kc < 256; kc += 32) {
        // Stage A tile: 128 rows x 32 k bf16 (16 B/thread)
#pragma unroll
        for (int u = 0; u < 2; u++) {
            const int cid = t + u * 256;
            const int row = cid >> 2, off = cid & 3;
            *(uint4*)&As[row * 40 + off * 8] =
                *(const uint4*)&xbf[(size_t)(m0 + row) * 256 + kc + off * 8];
        }
        // Stage W tile fp32 -> bf16
        {
            const int row = t >> 2, off = t & 3;
            const float* wp = &W[(size_t)(o0 + row) * 256 + kc + off * 8];
            const float4 a = *(const float4*)wp;
            const float4 c = *(const float4*)(wp + 4);
            uint4 o;
            o.x = f2bf(a.x) | ((unsigned)f2bf(a.y) << 16);
            o.y = f2bf(a.z) | ((unsigned)f2bf(a.w) << 16);
            o.z = f2bf(c.x) | ((unsigned)f2bf(c.y) << 16);
            o.w = f2bf(c.z) | ((unsigned)f2bf(c.w) << 16);
            *(uint4*)&Bs[row * 40 + off * 8] = o;
        }
        __syncthreads();
        short8 a[2], b[4];
#pragma unroll
        for (int rt = 0; rt < 2; rt++)
            a[rt] = *(const short8*)&As[(w * 32 + rt * 16 + l16) * 40 + quad * 8];
#pragma unroll
        for (int ct = 0; ct < 4; ct++)
            b[ct] = *(const short8*)&Bs[(ct * 16 + l16) * 40 + quad * 8];
#pragma unroll
        for (int rt = 0; rt < 2; rt++)
#pragma unroll
            for (int ct = 0; ct < 4; ct++)
                acc[rt][ct] = __builtin_amdgcn_mfma_f32_16x16x32_bf16(
                    a[rt], b[ct], acc[rt][ct], 0, 0, 0);
        __syncthreads();
    }

    // Epilogue: bias + bf16 into As (stride 72), then coalesced uint4 stores
#pragma unroll
    for (int rt = 0; rt < 2; rt++) {
#pragma unroll
        for (int ct = 0; ct < 4; ct++) {
            const int col = ct * 16 + l16;
            const float bb = bias[o0 + col];
#pragma unroll
            for (int reg = 0; reg < 4; reg++) {
                const int row = w * 32 + rt * 16 + quad * 4 + reg;
                As[row * 72 + col] = f2bf(acc[rt][ct][reg] + bb);
            }
        }
    }
    __syncthreads();
#pragma unroll
    for (int u = 0; u < 4; u++) {
        const int cid = t + u * 256;            // 0..1023
        const int row = cid >> 3;               // 0..127
        const int off = (cid & 7) * 8;          // 0..56 (ushorts)
        *(uint4*)&out[(size_t)(m0 + row) * 256 + o0 + off] =
            *(const uint4*)&As[row * 72 + off];
    }
}

// ---------------------------------------------------------------------------
// Top-40 + gather via RADIX-SELECT (R6-verified). grid (B), block 1024.
// kmat bf16; sel written fp32.
// ---------------------------------------------------------------------------
__global__ __launch_bounds__(1024) void topk_gather(const float* __restrict__ score,
                                                    const ushort_t* __restrict__ kmat,
                                                    float* __restrict__ sel) {
    const int b = blockIdx.x;
    const int t = threadIdx.x;
    __shared__ unsigned hist[256];
    __shared__ unsigned wsum[64];
    __shared__ unsigned sPrefix, sMask, sRem, sNeq;
    __shared__ int sNgt;
    __shared__ int top[NLM];
    __shared__ unsigned topkey[NLM];

    unsigned key[8];
#pragma unroll
    for (int j = 0; j < 8; j++) {
        const unsigned u = __float_as_uint(score[(size_t)b * SEQ + t + j * 1024]);
        key[j] = u ^ (unsigned)(((int)u >> 31) | 0x80000000);
    }
    if (t == 0) { sPrefix = 0; sMask = 0; sRem = NLM; sNgt = 0; sNeq = 0; }

    for (int lvl = 0; lvl < 4; lvl++) {
        const int shift = 24 - 8 * lvl;
        if (t < 256) hist[t] = 0;
        __syncthreads();
        const unsigned pfx = sPrefix, msk = sMask;
#pragma unroll
        for (int j = 0; j < 8; j++)
            if (((key[j] ^ pfx) & msk) == 0)
                atomicAdd(&hist[(key[j] >> shift) & 255u], 1u);
        __syncthreads();
        if (t < 64) wsum[t] = hist[t * 4] + hist[t * 4 + 1] + hist[t * 4 + 2] + hist[t * 4 + 3];
        __syncthreads();
        if (t == 0) {
            unsigned rem = sRem, cum = 0;
            int g = 63;
            for (; g > 0; g--) { if (cum + wsum[g] >= rem) break; cum += wsum[g]; }
            int d = g * 4 + 3;
            for (; d > g * 4; d--) { if (cum + hist[d] >= rem) break; cum += hist[d]; }
            sRem = rem - cum;
            sPrefix |= ((unsigned)d) << shift;
            sMask |= 255u << shift;
        }
        __syncthreads();
    }
    const unsigned K40 = sPrefix;
    const unsigned rem = sRem;
    const int ngt = NLM - (int)rem;

#pragma unroll
    for (int j = 0; j < 8; j++) {
        if (key[j] > K40) {
            const int slot = atomicAdd(&sNgt, 1);
            top[slot] = t + j * 1024; topkey[slot] = key[j];
        } else if (key[j] == K40) {
            const unsigned e = atomicAdd(&sNeq, 1u);
            if (e < rem) {
                const int slot = ngt + (int)e;
                top[slot] = t + j * 1024; topkey[slot] = key[j];
            }
        }
    }
    __syncthreads();

    if (t < 64) {
        unsigned long long c = (t < NLM)
            ? ((((unsigned long long)(~topkey[t])) << 32) | (unsigned)top[t])
            : 0xFFFFFFFFFFFFFFFFull;
#pragma unroll
        for (int kk = 2; kk <= 64; kk <<= 1) {
#pragma unroll
            for (int j = kk >> 1; j >= 1; j >>= 1) {
                const unsigned long long o = __shfl_xor(c, j);
                const bool takeMin = ((t & kk) == 0) == ((t & j) == 0);
                const bool less = c < o;
                c = (takeMin == less) ? c : o;
            }
        }
        if (t < NLM) top[t] = (int)(c & 0xFFFFFFFFu);
    }
    __syncthreads();

    for (int f = t; f < NLM * 256; f += 1024) {
        const int j = f >> 8;
        const int cc = f & 255;
        sel[(size_t)b * NLM * 256 + f] = bf2f(kmat[((size_t)b * SEQ + top[j]) * 256 + cc]);
    }
}

// ---------------------------------------------------------------------------
// sim_fused: grid (SEQ/64, B, 2), block 256. (R11-verified)
//   z=0: logits+softmax vs q -> write simq.
//   z=1: logits+softmax vs k -> tmat accumulation in-place (simk on-chip).
// LDS union: phase A (As_ 17.4K + St_ 10.9K) / phase B (Ps 10K + Vs 32K).
// ---------------------------------------------------------------------------
__global__ __launch_bounds__(256, 4) void sim_fused(const ushort_t* __restrict__ qbf,
                                                    const ushort_t* __restrict__ kbf,
                                                    const ushort_t* __restrict__ vbf,
                                                    const float* __restrict__ sel,
                                                    float* __restrict__ simq,
                                                    float* __restrict__ tmat) {
    __shared__ __align__(16) char smem[43008];
    float (*As_)[68] = (float(*)[68])smem;              // phase A: 17408 B
    float (*St_)[68] = (float(*)[68])(smem + 17408);    // phase A: 10880 B
    float (*Ps)[40]  = (float(*)[40])smem;              // phase B: 10240 B
    ushort_t* Vs     = (ushort_t*)(smem + 10240);       // phase B: 32768 B
    const int b = blockIdx.y;
    const int n0 = blockIdx.x * 64;
    const int t = threadIdx.x;
    const int r = t >> 2, c = t & 3;
    const ushort_t* __restrict__ A = (blockIdx.z == 0) ? qbf : kbf;
    const ushort_t* __restrict__ Arow = A + ((size_t)b * SEQ + n0) * 256;
    const float* __restrict__ Sb = sel + (size_t)b * NLM * 256;

    float acc[10];
#pragma unroll
    for (int j = 0; j < 10; j++) acc[j] = 0.f;

    for (int kc = 0; kc < 256; kc += 64) {
#pragma unroll
        for (int u = 0; u < 4; u++) {
            const int f = t + u * 256;
            const int row = f >> 4;
            const int c4 = (f & 15) * 4;
            const uint2 raw = *(const uint2*)&Arow[(size_t)row * 256 + kc + c4];
            float4 fa;
            fa.x = __uint_as_float((raw.x & 0xFFFFu) << 16);
            fa.y = __uint_as_float(raw.x & 0xFFFF0000u);
            fa.z = __uint_as_float((raw.y & 0xFFFFu) << 16);
            fa.w = __uint_as_float(raw.y & 0xFFFF0000u);
            *(float4*)&As_[row][c4] = fa;
        }
#pragma unroll
        for (int u = 0; u < 3; u++) {
            const int f = t + u * 256;
            if (f < 640) {
                const int row = f >> 4;
                const int c4 = (f & 15) * 4;
                *(float4*)&St_[row][c4] = *(const float4*)&Sb[(size_t)row * 256 + kc + c4];
            }
        }
        __syncthreads();
#pragma unroll 1
        for (int i = 0; i < 64; i += 4) {
            const float4 a = *(const float4*)&As_[r][i];
#pragma unroll
            for (int j = 0; j < 10; j++) {
                const float4 s = *(const float4*)&St_[c * 10 + j][i];
                acc[j] = fmaf(a.x, s.x, acc[j]);
                acc[j] = fmaf(a.y, s.y, acc[j]);
                acc[j] = fmaf(a.z, s.z, acc[j]);
                acc[j] = fmaf(a.w, s.w, acc[j]);
            }
        }
        __syncthreads();
    }

    float mx = -1e30f;
#pragma unroll
    for (int j = 0; j < 10; j++) {
        acc[j] *= INV_SCALE;
        mx = fmaxf(mx, acc[j]);
    }
    mx = fmaxf(mx, __shfl_xor(mx, 1));
    mx = fmaxf(mx, __shfl_xor(mx, 2));
    float sum = 0.f;
#pragma unroll
    for (int j = 0; j < 10; j++) {
        acc[j] = expf(acc[j] - mx);
        sum += acc[j];
    }
    sum += __shfl_xor(sum, 1);
    sum += __shfl_xor(sum, 2);
    const float inv = 1.f / sum;
#pragma unroll
    for (int j = 0; j < 10; j++) acc[j] *= inv;

    if (blockIdx.z == 0) {
        float* __restrict__ dst = &simq[((size_t)b * SEQ + n0 + r) * NLM + c * 10];
#pragma unroll
        for (int j2 = 0; j2 < 5; j2++) {
            float2 o; o.x = acc[2 * j2]; o.y = acc[2 * j2 + 1];
            *(float2*)&dst[2 * j2] = o;
        }
        return;
    }

    // ---- z=1: tmat accumulation in-place (simk stays on-chip) ----
#pragma unroll
    for (int j = 0; j < 10; j++) Ps[r][c * 10 + j] = acc[j];
#pragma unroll
    for (int u = 0; u < 8; u++) {
        const int cid = t + u * 256;          // 0..2047
        const int row = cid >> 5, off = (cid & 31) * 8;
        *(uint4*)&Vs[row * 256 + off] =
            *(const uint4*)&vbf[((size_t)b * SEQ + n0 + row) * 256 + off];
    }
    __syncthreads();

    float tac[40];
#pragma unroll
    for (int j = 0; j < 40; j++) tac[j] = 0.f;

#pragma unroll 2
    for (int m = 0; m < 64; m++) {
        const float vv = bf2f(Vs[m * 256 + t]);   // 2-way bank alias: free
#pragma unroll
        for (int j4 = 0; j4 < 10; j4++) {
            const float4 p = *(const float4*)&Ps[m][j4 * 4];  // broadcast
            tac[j4 * 4 + 0] = fmaf(p.x, vv, tac[j4 * 4 + 0]);
            tac[j4 * 4 + 1] = fmaf(p.y, vv, tac[j4 * 4 + 1]);
            tac[j4 * 4 + 2] = fmaf(p.z, vv, tac[j4 * 4 + 2]);
            tac[j4 * 4 + 3] = fmaf(p.w, vv, tac[j4 * 4 + 3]);
        }
    }
#pragma unroll
    for (int j = 0; j < 40; j++)
        atomicAdd(&tmat[(size_t)b * NLM * 256 + j * 256 + t], tac[j]);
}

// ---------------------------------------------------------------------------
// out_pre[g][cc] = sum_l simq[g][l] * t[b][l][cc] -> bf16 (feeds final GEMM).
// grid (MROWS/64), block 256.
// R13 lesson: the TW reassociation (tw_kernel+out_final) replacing this pair
// measured +7 us vs this tail (8-block tw is latency-bound + extra launch);
// keeping the R11 out_pre + MFMA gemm_out tail.
// ---------------------------------------------------------------------------
__global__ __launch_bounds__(256) void out_pre_kernel(const float* __restrict__ simq,
                                                      const float* __restrict__ tmat,
                                                      ushort_t* __restrict__ outp_bf) {
    __shared__ float Pm[64][40];
    const int g0 = blockIdx.x * 64;
    const int b = g0 >> 13;
    const int t = threadIdx.x;
    float* pflat = &Pm[0][0];
    for (int f = t; f < 64 * NLM; f += 256) pflat[f] = simq[(size_t)g0 * NLM + f];
    float tc[40];
#pragma unroll
    for (int l = 0; l < 40; l++) tc[l] = tmat[(size_t)b * NLM * 256 + l * 256 + t];
    __syncthreads();
#pragma unroll 2
    for (int m = 0; m < 64; m++) {
        float a = 0.f;
#pragma unroll
        for (int j4 = 0; j4 < 10; j4++) {
            const float4 p = *(const float4*)&Pm[m][j4 * 4];
            a = fmaf(p.x, tc[j4 * 4 + 0], a);
            a = fmaf(p.y, tc[j4 * 4 + 1], a);
            a = fmaf(p.z, tc[j4 * 4 + 2], a);
            a = fmaf(p.w, tc[j4 * 4 + 3], a);
        }
        outp_bf[((size_t)g0 + m) * 256 + t] = f2bf(a);
    }
}

// ---------------------------------------------------------------------------
// gemm_out: final projection. A bf16, Wo fp32 (converted during staging),
// fp32 out with bias + residual via LDS-transpose epilogue. grid (4, 128).
// ---------------------------------------------------------------------------
__global__ __launch_bounds__(256) void gemm_out(const ushort_t* __restrict__ Abf,
                                                const float* __restrict__ Wo,
                                                const float* __restrict__ bias,
                                                const float* __restrict__ resid,
                                                float* __restrict__ out) {
    __shared__ __align__(16) char smem[128 * 68 * 4];   // 34.8 KB
    ushort_t* As = (ushort_t*)smem;                      // 10 KB  (128*40)
    ushort_t* Bs = (ushort_t*)(smem + 128 * 40 * 2);     // 5 KB   (64*40)
    float* Ft = (float*)smem;                            // 128*68 floats
    const int t = threadIdx.x;
    const int o0 = blockIdx.x * 64;
    const int m0 = blockIdx.y * 128;
    const int lane = t & 63;
    const int w = t >> 6;
    const int quad = lane >> 4;
    const int l16 = lane & 15;

    floatx4 acc[2][4];
#pragma unroll
    for (int rt = 0; rt < 2; rt++)
#pragma unroll
        for (int ct = 0; ct < 4; ct++) acc[rt][ct] = (floatx4){0.f, 0.f, 0.f, 0.f};

    for (int kc = 0; kc < 256; kc += 32) {
#pragma unroll
        for (int u = 0; u < 2; u++) {
            const int cid = t + u * 256;
            const int row = cid >> 2, off = cid & 3;
            *(uint4*)&As[row * 40 + off * 8] =
                *(const uint4*)&Abf[(size_t)(m0 + row) * 256 + kc + off * 8];
        }
        {
            const int row = t >> 2, off = t & 3;
            const float* wp = &Wo[(size_t)(o0 + row) * 256 + kc + off * 8];
            const float4 a = *(const float4*)wp;
            const float4 c = *(const float4*)(wp + 4);
            uint4 o;
            o.x = f2bf(a.x) | ((unsigned)f2bf(a.y) << 16);
            o.y = f2bf(a.z) | ((unsigned)f2bf(a.w) << 16);
            o.z = f2bf(c.x) | ((unsigned)f2bf(c.y) << 16);
            o.w = f2bf(c.z) | ((unsigned)f2bf(c.w) << 16);
            *(uint4*)&Bs[row * 40 + off * 8] = o;
        }
        __syncthreads();
        short8 a[2], b[4];
#pragma unroll
        for (int rt = 0; rt < 2; rt++)
            a[rt] = *(const short8*)&As[(w * 32 + rt * 16 + l16) * 40 + quad * 8];
#pragma unroll
        for (int ct = 0; ct < 4; ct++)
            b[ct] = *(const short8*)&Bs[(ct * 16 + l16) * 40 + quad * 8];
#pragma unroll
        for (int rt = 0; rt < 2; rt++)
#pragma unroll
            for (int ct = 0; ct < 4; ct++)
                acc[rt][ct] = __builtin_amdgcn_mfma_f32_16x16x32_bf16(
                    a[rt], b[ct], acc[rt][ct], 0, 0, 0);
        __syncthreads();
    }

    // Epilogue: bias into Ft (stride 68), then float4 stores with resid add
#pragma unroll
    for (int rt = 0; rt < 2; rt++) {
#pragma unroll
        for (int ct = 0; ct < 4; ct++) {
            const int col = ct * 16 + l16;
            const float bb = bias[o0 + col];
#pragma unroll
            for (int reg = 0; reg < 4; reg++) {
                const int row = w * 32 + rt * 16 + quad * 4 + reg;
                Ft[row * 68 + col] = acc[rt][ct][reg] + bb;
            }
        }
    }
    __syncthreads();
#pragma unroll
    for (int u = 0; u < 8; u++) {
        const int cid = t + u * 256;            // 0..2047
        const int row = cid >> 4;               // 0..127
        const int off = (cid & 15) * 4;         // 0..60 (floats)
        const float4 v = *(const float4*)&Ft[row * 68 + off];
        const float4 r4 = *(const float4*)&resid[(size_t)(m0 + row) * 256 + o0 + off];
        float4 o;
        o.x = v.x + r4.x; o.y = v.y + r4.y; o.z = v.z + r4.z; o.w = v.w + r4.w;
        *(float4*)&out[(size_t)(m0 + row) * 256 + o0 + off] = o;
    }
}

// ---------------------------------------------------------------------------
// Workspace (~37 MB). 7 dispatches — exact revert to R11 (best measured:
// 204.7 us). R12 (xbf folded into GEMMs) and R13 (TW reassociation) both
// measured slower; every structural deviation from this config regressed.
// outp_bf ALIASES xbf (dead after gemm_qkv_score).
// ---------------------------------------------------------------------------
extern "C" void kernel_launch(void* const* d_in, const int* in_sizes, int n_in,
                              void* d_out, int out_size, void* d_ws, size_t ws_size,
                              hipStream_t stream) {
    const float* query = (const float*)d_in[0];
    const float* Wq = (const float*)d_in[1];
    const float* bq = (const float*)d_in[2];
    const float* Wk = (const float*)d_in[3];
    const float* bk = (const float*)d_in[4];
    const float* Wv = (const float*)d_in[5];
    const float* bv = (const float*)d_in[6];
    const float* Wo = (const float*)d_in[7];
    const float* bo = (const float*)d_in[8];
    float* out = (float*)d_out;

    char* p = (char*)d_ws;
    float* simq  = (float*)p;            p += (size_t)MROWS * NLM * 4;      // 2.62 MB
    float* sel   = (float*)p;            p += (size_t)BATCH * NLM * 256 * 4;
    float* tmat  = (float*)p;            p += (size_t)BATCH * NLM * 256 * 4;
    float* partial = (float*)p;          p += (size_t)BATCH * NCBLK * 256 * 4; // 512 KB
    float* ws    = (float*)p;            p += (size_t)BATCH * 256 * 4;
    float* score = (float*)p;            p += (size_t)BATCH * SEQ * 4;
    ushort_t* qkv = (ushort_t*)p;        p += (size_t)3 * MROWS * 256 * 2;  // 25.2 MB
    ushort_t* xbf = (ushort_t*)p;        p += (size_t)MROWS * 256 * 2;      // 8.39 MB
    ushort_t* qbf = qkv;
    ushort_t* kbf = qkv + (size_t)MROWS * 256;
    ushort_t* vbf = qkv + (size_t)2 * MROWS * 256;
    ushort_t* outp_bf = xbf;  // alias: xbf dead after gemm_qkv_score

    const dim3 blk(256);

    convert_colsum<<<dim3(SEQ / 32, BATCH), blk, 0, stream>>>(query, xbf, partial);
    ws_kernel<<<dim3(BATCH), dim3(1024), 0, stream>>>(partial, Wq, bq, Wk, ws, tmat);

    gemm_qkv_score<<<dim3(4, MROWS / 128, 4), blk, 0, stream>>>(
        xbf, Wq, Wk, Wv, bq, bk, bv, qkv, query, ws, score);

    topk_gather<<<dim3(BATCH), dim3(1024), 0, stream>>>(score, kbf, sel);

    sim_fused<<<dim3(SEQ / 64, BATCH, 2), blk, 0, stream>>>(qbf, kbf, vbf, sel, simq, tmat);

    out_pre_kernel<<<dim3(MROWS / 64), blk, 0, stream>>>(simq, tmat, outp_bf);
    gemm_out<<<dim3(4, MROWS / 128), blk, 0, stream>>>(outp_bf, Wo, bo, query, out);
}